// Round 14
// baseline (166.486 us; speedup 1.0000x reference)
//
#include <hip/hip_runtime.h>

#define NN   50000
#define MPAD 50048   // 782 * 64
#define ZR   NN      // zero-row index (gemm writes zeros there via scale=0)

#define NB    196    // destination buckets: col >> 8
#define SLOTS 48
#define PT_T  512
#define PT_TILE 4096
#define CAP   5888   // fixed per-bucket region capacity (mean 4082, +28 sigma)
#define BT    256

#define AGG_BLOCKS 2048   // 8 blocks/CU x 256 CU, all co-resident; waves grid-stride

typedef __attribute__((ext_vector_type(8))) short bf16x8;
typedef __attribute__((ext_vector_type(4))) float f32x4;
typedef unsigned int  u32;
typedef unsigned short u16;

__device__ __forceinline__ u16 f2bf(float f) {
    u32 u = __float_as_uint(f);
    return (u16)((u + 0x7fffu + ((u >> 16) & 1u)) >> 16);
}
__device__ __forceinline__ float bflo(u32 u) { return __uint_as_float(u << 16); }
__device__ __forceinline__ float bfhi(u32 u) { return __uint_as_float(u & 0xffff0000u); }
__device__ __forceinline__ u32 pack2(float x, float y) {
    return (u32)f2bf(x) | ((u32)f2bf(y) << 16);
}

// ---------------- fused prep: W1t, W2t bf16 transposes + cursor zeroing ----------------
#define PREP_W1 (144 * 128)
#define PREP_W2 (144 * 160)

__global__ void k_prep(const float* __restrict__ W1, const float* __restrict__ Wp,
                       const float* __restrict__ W2,
                       u16* __restrict__ W1t, u16* __restrict__ W2t,
                       int* __restrict__ gcursor) {
    int i = blockIdx.x * blockDim.x + threadIdx.x;
    if (i < PREP_W1) {
        int n = i >> 7, k = i & 127;
        float v = 0.f;
        if (n < 128) v = W1[k * 128 + n];
        else if (n < 132) v = Wp[k * 4 + (n - 128)];
        W1t[i] = f2bf(v);
        return;
    }
    i -= PREP_W1;
    if (i < PREP_W2) {
        int n = i / 160, k = i - n * 160;
        float v = (n < 132 && k < 132) ? W2[k * 132 + n] : 0.f;
        W2t[i] = f2bf(v);
        return;
    }
    i -= PREP_W2;
    if (i < NB) gcursor[i] = 0;
}

// ---------------- partition: direct append into fixed-capacity bucket regions ----------------
// rec = (col&255)<<24 | row
__global__ __launch_bounds__(PT_T) void k_part(const int* __restrict__ erow,
                                               const int* __restrict__ ecol, int E,
                                               int* __restrict__ gcursor,
                                               u32* __restrict__ recs) {
    __shared__ int lcnt[NB];
    __shared__ int bbase[NB];
    __shared__ u32 rbuf[NB * SLOTS];
    int tid = threadIdx.x;
    for (int i = tid; i < NB; i += PT_T) lcnt[i] = 0;
    __syncthreads();
    int e0 = blockIdx.x * PT_TILE;
#pragma unroll
    for (int j = 0; j < PT_TILE / PT_T; ++j) {
        int e = e0 + j * PT_T + tid;
        if (e < E) {
            int c = ecol[e];
            u32 rec = ((u32)(c & 255) << 24) | (u32)erow[e];
            int b = c >> 8;
            int pos = atomicAdd(&lcnt[b], 1);
            if (pos < SLOTS) rbuf[b * SLOTS + pos] = rec;
            else {  // staging overflow: direct global emit
                int g = atomicAdd(&gcursor[b], 1);
                if (g < CAP) recs[(size_t)b * CAP + g] = rec;
            }
        }
    }
    __syncthreads();
    if (tid < NB) {
        int n = lcnt[tid]; if (n > SLOTS) n = SLOTS;
        bbase[tid] = n ? atomicAdd(&gcursor[tid], n) : 0;
    }
    __syncthreads();
    int wave = tid >> 6, lane = tid & 63;
    for (int b = wave; b < NB; b += PT_T / 64) {
        int n = lcnt[b]; if (n > SLOTS) n = SLOTS;
        if (lane < n) {
            int g = bbase[b] + lane;
            if (g < CAP) recs[(size_t)b * CAP + g] = rbuf[b * SLOTS + lane];
        }
    }
}

// per-bucket: self-computed bucket prefix -> count -> scan -> starts/dinv
// -> LDS scatter -> coalesced compacted out (bscan folded in)
__global__ __launch_bounds__(BT) void k_build(const u32* __restrict__ recs,
                                              const int* __restrict__ gcursor,
                                              int* __restrict__ starts,
                                              float* __restrict__ dinv,
                                              u32* __restrict__ ec) {
    __shared__ u32 rbuf[CAP];
    __shared__ u32 obuf[CAP];
    __shared__ int bc[256];
    __shared__ int ncnt[256];
    __shared__ int a[256];
    __shared__ int ncur[256];
    int tid = threadIdx.x, b = blockIdx.x;

    // bucket-count scan (every block computes the same 196-prefix)
    int c = 0;
    if (tid < NB) { c = gcursor[tid]; if (c > CAP) c = CAP; }
    bc[tid] = c;
    __syncthreads();
    for (int off = 1; off < 256; off <<= 1) {
        int add = (tid >= off) ? bc[tid - off] : 0;
        __syncthreads();
        bc[tid] += add;
        __syncthreads();
    }
    if (b == 0 && tid == NB - 1) starts[NN] = bc[tid];
    int cb = gcursor[b]; if (cb > CAP) cb = CAP;
    int lo = bc[b] - cb;
    int cnt = cb;

    const u32* src = recs + (size_t)b * CAP;
    for (int i = tid; i < cnt; i += BT) rbuf[i] = src[i];
    ncnt[tid] = 0;
    __syncthreads();
    for (int i = tid; i < cnt; i += BT) atomicAdd(&ncnt[rbuf[i] >> 24], 1);
    __syncthreads();
    a[tid] = ncnt[tid];
    __syncthreads();
    for (int off = 1; off < 256; off <<= 1) {
        int add = (tid >= off) ? a[tid - off] : 0;
        __syncthreads();
        a[tid] += add;
        __syncthreads();
    }
    int excl = a[tid] - ncnt[tid];
    ncur[tid] = excl;
    {
        int node = (b << 8) + tid;
        if (node < NN) {
            starts[node] = lo + excl;
            float d = (float)ncnt[tid] + 1.0f;
            dinv[node] = rsqrtf(d);
        }
    }
    __syncthreads();
    for (int i = tid; i < cnt; i += BT) {
        u32 rec = rbuf[i];
        int pos = atomicAdd(&ncur[rec >> 24], 1);
        if (pos >= 0 && pos < CAP) obuf[pos] = rec & 0xFFFFFFu;
    }
    __syncthreads();
    for (int i = tid; i < cnt; i += BT) ec[lo + i] = obuf[i];
}

// ---------------- MFMA GEMM, fused dinv row-scaling; pad rows scale=0 -> zeros ----------------
template<int K, bool CONVF32, bool SCALE_EXT>
__global__ __launch_bounds__(256) void k_gemm_mfma(const void* __restrict__ Ain,
                                                   const u16* __restrict__ Bt,
                                                   const float* __restrict__ rs,
                                                   u16* __restrict__ Cmain,
                                                   u16* __restrict__ Cext) {
    int lane = threadIdx.x & 63;
    int wv = threadIdx.x >> 6;
    int rbase = blockIdx.x * 64 + wv * 16;
    int lr = lane & 15;
    int kk = (lane >> 4) * 8;
    int arow = rbase + lr;
    if (CONVF32 && arow >= NN) arow = NN - 1;

    const u16* bp = Bt + (size_t)lr * K + kk;

    f32x4 acc[9] = {};
#pragma unroll
    for (int ks = 0; ks < K / 32; ++ks) {
        bf16x8 af;
        if (CONVF32) {
            const float* ap = (const float*)Ain + (size_t)arow * K + kk + ks * 32;
            float4 f0 = *(const float4*)ap;
            float4 f1 = *(const float4*)(ap + 4);
            union { uint4 u; bf16x8 v; } cv;
            cv.u.x = pack2(f0.x, f0.y); cv.u.y = pack2(f0.z, f0.w);
            cv.u.z = pack2(f1.x, f1.y); cv.u.w = pack2(f1.z, f1.w);
            af = cv.v;
        } else {
            af = *(const bf16x8*)((const u16*)Ain + (size_t)arow * K + kk + ks * 32);
        }
#pragma unroll
        for (int t = 0; t < 9; ++t) {
            bf16x8 bf = *(const bf16x8*)(bp + (size_t)(t * 16) * K + ks * 32);
            acc[t] = __builtin_amdgcn_mfma_f32_16x16x32_bf16(bf, af, acc[t], 0, 0, 0);
        }
    }

    int n0 = (lane >> 4) * 4;
    int crow = rbase + lr;
    float s = (crow < NN) ? rs[crow] : 0.0f;   // pad rows -> exact zeros
    u16* cm = Cmain + (size_t)crow * 128;
#pragma unroll
    for (int t = 0; t < 8; ++t) {
        ushort4 w;
        w.x = f2bf(acc[t][0] * s); w.y = f2bf(acc[t][1] * s);
        w.z = f2bf(acc[t][2] * s); w.w = f2bf(acc[t][3] * s);
        *(ushort4*)(cm + 16 * t + n0) = w;
    }
    if (n0 == 0) {
        float se = SCALE_EXT ? s : ((crow < NN) ? 1.0f : 0.0f);
        ushort4 w;
        w.x = f2bf(acc[8][0] * se); w.y = f2bf(acc[8][1] * se);
        w.z = f2bf(acc[8][2] * se); w.w = f2bf(acc[8][3] * se);
        *(ushort4*)(Cext + (size_t)crow * 4) = w;
    }
}

// ---------------- aggregates: grid-stride waves (balance), quarter-wave gathers ----------------

__global__ __launch_bounds__(256) void k_agg1(const u16* __restrict__ Hm,
                       const u16* __restrict__ Xp,
                       const int* __restrict__ starts, const u32* __restrict__ ec,
                       const float* __restrict__ dinv,
                       const float* __restrict__ b1, u16* __restrict__ outp) {
    int lane = threadIdx.x & 63;
    int gwave = blockIdx.x * (blockDim.x >> 6) + (threadIdx.x >> 6);
    int nwaves = gridDim.x * (blockDim.x >> 6);
    int c16 = lane & 15;
    int q = lane >> 4;

    for (int node = gwave; node < MPAD; node += nwaves) {
        u32* orow = (u32*)(outp + (size_t)node * 160);
        if (node >= NN) {              // zero Hcat pad row
            if (lane < 16) {
                *(uint4*)(orow + c16 * 4) = make_uint4(0, 0, 0, 0);
                orow[64 + lane] = 0;
            }
            continue;
        }
        int s = starts[node], e = starts[node + 1];

        float a0=0,a1=0,a2=0,a3=0,a4=0,a5=0,a6=0,a7=0;
        if (lane < 16) {
            uint4 v = *(const uint4*)(Hm + ((size_t)node << 7) + c16 * 8);
            a0 = bflo(v.x); a1 = bfhi(v.x); a2 = bflo(v.y); a3 = bfhi(v.y);
            a4 = bflo(v.z); a5 = bfhi(v.z); a6 = bflo(v.w); a7 = bfhi(v.w);
        }

        for (int g0 = s; g0 < e; g0 += 16) {
            u32 row[4];
#pragma unroll
            for (int grp = 0; grp < 4; ++grp) {
                int idx = g0 + grp * 4 + q;
                int ii = idx < e ? idx : e - 1;
                u32 r = ec[ii];
                row[grp] = (idx < e) ? r : (u32)ZR;
            }
            uint4 v[4];
#pragma unroll
            for (int grp = 0; grp < 4; ++grp)
                v[grp] = *(const uint4*)(Hm + ((size_t)row[grp] << 7) + c16 * 8);
#pragma unroll
            for (int grp = 0; grp < 4; ++grp) {
                a0 += bflo(v[grp].x); a1 += bfhi(v[grp].x);
                a2 += bflo(v[grp].y); a3 += bfhi(v[grp].y);
                a4 += bflo(v[grp].z); a5 += bfhi(v[grp].z);
                a6 += bflo(v[grp].w); a7 += bfhi(v[grp].w);
            }
        }

        a0 += __shfl_xor(a0, 16); a1 += __shfl_xor(a1, 16);
        a2 += __shfl_xor(a2, 16); a3 += __shfl_xor(a3, 16);
        a4 += __shfl_xor(a4, 16); a5 += __shfl_xor(a5, 16);
        a6 += __shfl_xor(a6, 16); a7 += __shfl_xor(a7, 16);
        a0 += __shfl_xor(a0, 32); a1 += __shfl_xor(a1, 32);
        a2 += __shfl_xor(a2, 32); a3 += __shfl_xor(a3, 32);
        a4 += __shfl_xor(a4, 32); a5 += __shfl_xor(a5, 32);
        a6 += __shfl_xor(a6, 32); a7 += __shfl_xor(a7, 32);

        float dc = dinv[node];
        float4 bA = *(const float4*)(b1 + c16 * 8);
        float4 bB = *(const float4*)(b1 + c16 * 8 + 4);
        float v0 = fmaxf(fmaf(dc, a0, bA.x), 0.f);
        float v1 = fmaxf(fmaf(dc, a1, bA.y), 0.f);
        float v2 = fmaxf(fmaf(dc, a2, bA.z), 0.f);
        float v3 = fmaxf(fmaf(dc, a3, bA.w), 0.f);
        float v4 = fmaxf(fmaf(dc, a4, bB.x), 0.f);
        float v5 = fmaxf(fmaf(dc, a5, bB.y), 0.f);
        float v6 = fmaxf(fmaf(dc, a6, bB.z), 0.f);
        float v7 = fmaxf(fmaf(dc, a7, bB.w), 0.f);

        if (lane < 16) {
            uint4 w = make_uint4(pack2(v0, v1), pack2(v2, v3), pack2(v4, v5), pack2(v6, v7));
            *(uint4*)(orow + c16 * 4) = w;
            orow[64 + lane] = (lane < 2) ? *(const u32*)(Xp + ((size_t)node << 2) + 2 * lane) : 0u;
        }
    }
}

__global__ __launch_bounds__(256) void k_agg2(const u16* __restrict__ Hm,
                       const u16* __restrict__ He,
                       const u16* __restrict__ Xp1,
                       const int* __restrict__ starts, const u32* __restrict__ ec,
                       const float* __restrict__ dinv,
                       const float* __restrict__ b2, float* __restrict__ outp) {
    int lane = threadIdx.x & 63;
    int gwave = blockIdx.x * (blockDim.x >> 6) + (threadIdx.x >> 6);
    int nwaves = gridDim.x * (blockDim.x >> 6);
    int c16 = lane & 15;
    int q = lane >> 4;

    for (int node = gwave; node < NN; node += nwaves) {
        int s = starts[node], e = starts[node + 1];

        float a0=0,a1=0,a2=0,a3=0,a4=0,a5=0,a6=0,a7=0;
        float cx = 0.f, cy = 0.f;
        if (lane < 16) {
            uint4 v = *(const uint4*)(Hm + ((size_t)node << 7) + c16 * 8);
            a0 = bflo(v.x); a1 = bfhi(v.x); a2 = bflo(v.y); a3 = bfhi(v.y);
            a4 = bflo(v.z); a5 = bfhi(v.z); a6 = bflo(v.w); a7 = bfhi(v.w);
        }
        if (lane < 2) {
            u32 w = *(const u32*)(He + ((size_t)node << 2) + 2 * lane);
            cx = bflo(w); cy = bfhi(w);
        }

        for (int g0 = s; g0 < e; g0 += 16) {
            u32 row[4];
#pragma unroll
            for (int grp = 0; grp < 4; ++grp) {
                int idx = g0 + grp * 4 + q;
                int ii = idx < e ? idx : e - 1;
                u32 r = ec[ii];
                row[grp] = (idx < e) ? r : (u32)ZR;
            }
            uint4 v[4];
#pragma unroll
            for (int grp = 0; grp < 4; ++grp)
                v[grp] = *(const uint4*)(Hm + ((size_t)row[grp] << 7) + c16 * 8);
            if (c16 < 2) {
#pragma unroll
                for (int grp = 0; grp < 4; ++grp) {
                    u32 w = *(const u32*)(He + ((size_t)row[grp] << 2) + 2 * (lane & 1));
                    cx += bflo(w); cy += bfhi(w);
                }
            }
#pragma unroll
            for (int grp = 0; grp < 4; ++grp) {
                a0 += bflo(v[grp].x); a1 += bfhi(v[grp].x);
                a2 += bflo(v[grp].y); a3 += bfhi(v[grp].y);
                a4 += bflo(v[grp].z); a5 += bfhi(v[grp].z);
                a6 += bflo(v[grp].w); a7 += bfhi(v[grp].w);
            }
        }

        a0 += __shfl_xor(a0, 16); a1 += __shfl_xor(a1, 16);
        a2 += __shfl_xor(a2, 16); a3 += __shfl_xor(a3, 16);
        a4 += __shfl_xor(a4, 16); a5 += __shfl_xor(a5, 16);
        a6 += __shfl_xor(a6, 16); a7 += __shfl_xor(a7, 16);
        cx += __shfl_xor(cx, 16); cy += __shfl_xor(cy, 16);
        a0 += __shfl_xor(a0, 32); a1 += __shfl_xor(a1, 32);
        a2 += __shfl_xor(a2, 32); a3 += __shfl_xor(a3, 32);
        a4 += __shfl_xor(a4, 32); a5 += __shfl_xor(a5, 32);
        a6 += __shfl_xor(a6, 32); a7 += __shfl_xor(a7, 32);
        cx += __shfl_xor(cx, 32); cy += __shfl_xor(cy, 32);

        float dc = dinv[node];
        float* orow = outp + (size_t)node * 136;
        if (lane < 16) {
            float4 bA = *(const float4*)(b2 + c16 * 8);
            float4 bB = *(const float4*)(b2 + c16 * 8 + 4);
            float4 wA, wB;
            wA.x = fmaf(dc, a0, bA.x); wA.y = fmaf(dc, a1, bA.y);
            wA.z = fmaf(dc, a2, bA.z); wA.w = fmaf(dc, a3, bA.w);
            wB.x = fmaf(dc, a4, bB.x); wB.y = fmaf(dc, a5, bB.y);
            wB.z = fmaf(dc, a6, bB.z); wB.w = fmaf(dc, a7, bB.w);
            *(float4*)(orow + c16 * 8) = wA;
            *(float4*)(orow + c16 * 8 + 4) = wB;
        }
        if (lane < 2) {
            float2 bb = *(const float2*)(b2 + 128 + 2 * lane);
            *(float2*)(orow + 128 + 2 * lane) = make_float2(fmaf(dc, cx, bb.x), fmaf(dc, cy, bb.y));
            u32 up = *(const u32*)(Xp1 + ((size_t)node << 2) + 2 * lane);
            *(float2*)(orow + 132 + 2 * lane) = make_float2(bflo(up), bfhi(up));
        }
    }
}

extern "C" void kernel_launch(void* const* d_in, const int* in_sizes, int n_in,
                              void* d_out, int out_size, void* d_ws, size_t ws_size,
                              hipStream_t stream) {
    const int*   ei = (const int*)d_in[0];
    const float* x  = (const float*)d_in[1];
    const float* Wp = (const float*)d_in[2];
    const float* W1 = (const float*)d_in[3];
    const float* b1 = (const float*)d_in[4];
    const float* W2 = (const float*)d_in[5];
    const float* b2 = (const float*)d_in[6];
    float* out = (float*)d_out;

    const int E = in_sizes[0] / 2;
    const int* erow = ei;
    const int* ecol = ei + E;

    // workspace layout
    char* p = (char*)d_ws;
    u16* H1main = (u16*)p; p += (size_t)MPAD * 128 * 2;  // conv1 h' (scaled); reused as H2main
    u16* Hcat   = (u16*)p; p += (size_t)MPAD * 160 * 2;  // h1cat bf16
    u16* Xp1    = (u16*)p; p += (size_t)MPAD * 4 * 2;    // xproj bf16
    u16* H2ext  = (u16*)p; p += (size_t)MPAD * 4 * 2;    // h2' cols 128-131 (scaled)
    u16* W1t    = (u16*)p; p += 144 * 128 * 2;
    u16* W2t    = (u16*)p; p += 144 * 160 * 2;
    u32* recs   = (u32*)p; p += (size_t)NB * CAP * 4;    // fixed-capacity bucket regions
    u32* ec     = (u32*)p; p += (size_t)E * 4;           // compacted row-only records
    float* dinv = (float*)p; p += NN * 4;
    int* starts = (int*)p; p += (size_t)(NN + 1) * 4;
    int* gcursor= (int*)p; p += NB * 4;

    u16* H2main = H1main;

    const int T = 256;
    const int pblocks = (E + PT_TILE - 1) / PT_TILE;

    // fused prep (weights + cursor zero)
    const int prep_total = PREP_W1 + PREP_W2 + NB;
    k_prep<<<(prep_total + T - 1) / T, T, 0, stream>>>(W1, Wp, W2, W1t, W2t, gcursor);

    // CSR build: partition -> build (bscan folded into build)
    k_part<<<pblocks, PT_T, 0, stream>>>(erow, ecol, E, gcursor, recs);
    k_build<<<NB, BT, 0, stream>>>(recs, gcursor, starts, dinv, ec);

    const int gblocks = MPAD / 64;

    // conv1: h' = dinv .* (x @ [W1|Wp]); pad rows = 0
    k_gemm_mfma<128, true, false><<<gblocks, T, 0, stream>>>(x, W1t, dinv, H1main, Xp1);
    k_agg1<<<AGG_BLOCKS, T, 0, stream>>>(H1main, Xp1, starts, ec, dinv, b1, Hcat);

    // conv2: h2' = dinv .* (h1cat @ W2); pad rows = 0 (incl. ext)
    k_gemm_mfma<160, false, true><<<gblocks, T, 0, stream>>>(Hcat, W2t, dinv, H2main, H2ext);
    k_agg2<<<AGG_BLOCKS, T, 0, stream>>>(H2main, H2ext, Xp1, starts, ec, dinv, b2, out);
}

// Round 15
// 146.157 us; speedup vs baseline: 1.1391x; 1.1391x over previous
//
#include <hip/hip_runtime.h>

#define NN   50000
#define MPAD 50048   // 782 * 64
#define ZR   NN      // zero-row index (gemm writes zeros there via scale=0)

#define NB    196    // destination buckets: col >> 8
#define SLOTS 48
#define PT_T  512
#define PT_TILE 4096
#define CAP   5888   // fixed per-bucket region capacity (mean 4082, +28 sigma)
#define BT    256

#define AT    128    // agg block: 2 waves -> less tail imbalance per CU slot, same VGPR

typedef __attribute__((ext_vector_type(8))) short bf16x8;
typedef __attribute__((ext_vector_type(4))) float f32x4;
typedef unsigned int  u32;
typedef unsigned short u16;

__device__ __forceinline__ u16 f2bf(float f) {
    u32 u = __float_as_uint(f);
    return (u16)((u + 0x7fffu + ((u >> 16) & 1u)) >> 16);
}
__device__ __forceinline__ float bflo(u32 u) { return __uint_as_float(u << 16); }
__device__ __forceinline__ float bfhi(u32 u) { return __uint_as_float(u & 0xffff0000u); }
__device__ __forceinline__ u32 pack2(float x, float y) {
    return (u32)f2bf(x) | ((u32)f2bf(y) << 16);
}

// ---------------- fused prep: W1t, W2t bf16 transposes + cursor zeroing ----------------
#define PREP_W1 (144 * 128)
#define PREP_W2 (144 * 160)

__global__ void k_prep(const float* __restrict__ W1, const float* __restrict__ Wp,
                       const float* __restrict__ W2,
                       u16* __restrict__ W1t, u16* __restrict__ W2t,
                       int* __restrict__ gcursor) {
    int i = blockIdx.x * blockDim.x + threadIdx.x;
    if (i < PREP_W1) {
        int n = i >> 7, k = i & 127;
        float v = 0.f;
        if (n < 128) v = W1[k * 128 + n];
        else if (n < 132) v = Wp[k * 4 + (n - 128)];
        W1t[i] = f2bf(v);
        return;
    }
    i -= PREP_W1;
    if (i < PREP_W2) {
        int n = i / 160, k = i - n * 160;
        float v = (n < 132 && k < 132) ? W2[k * 132 + n] : 0.f;
        W2t[i] = f2bf(v);
        return;
    }
    i -= PREP_W2;
    if (i < NB) gcursor[i] = 0;
}

// ---------------- partition: direct append into fixed-capacity bucket regions ----------------
// rec = (col&255)<<24 | row
__global__ __launch_bounds__(PT_T) void k_part(const int* __restrict__ erow,
                                               const int* __restrict__ ecol, int E,
                                               int* __restrict__ gcursor,
                                               u32* __restrict__ recs) {
    __shared__ int lcnt[NB];
    __shared__ int bbase[NB];
    __shared__ u32 rbuf[NB * SLOTS];
    int tid = threadIdx.x;
    for (int i = tid; i < NB; i += PT_T) lcnt[i] = 0;
    __syncthreads();
    int e0 = blockIdx.x * PT_TILE;
#pragma unroll
    for (int j = 0; j < PT_TILE / PT_T; ++j) {
        int e = e0 + j * PT_T + tid;
        if (e < E) {
            int c = ecol[e];
            u32 rec = ((u32)(c & 255) << 24) | (u32)erow[e];
            int b = c >> 8;
            int pos = atomicAdd(&lcnt[b], 1);
            if (pos < SLOTS) rbuf[b * SLOTS + pos] = rec;
            else {  // staging overflow: direct global emit
                int g = atomicAdd(&gcursor[b], 1);
                if (g < CAP) recs[(size_t)b * CAP + g] = rec;
            }
        }
    }
    __syncthreads();
    if (tid < NB) {
        int n = lcnt[tid]; if (n > SLOTS) n = SLOTS;
        bbase[tid] = n ? atomicAdd(&gcursor[tid], n) : 0;
    }
    __syncthreads();
    int wave = tid >> 6, lane = tid & 63;
    for (int b = wave; b < NB; b += PT_T / 64) {
        int n = lcnt[b]; if (n > SLOTS) n = SLOTS;
        if (lane < n) {
            int g = bbase[b] + lane;
            if (g < CAP) recs[(size_t)b * CAP + g] = rbuf[b * SLOTS + lane];
        }
    }
}

// per-bucket: self-computed bucket prefix -> count -> scan -> starts/dinv
// -> LDS scatter -> coalesced compacted out (bscan folded in)
__global__ __launch_bounds__(BT) void k_build(const u32* __restrict__ recs,
                                              const int* __restrict__ gcursor,
                                              int* __restrict__ starts,
                                              float* __restrict__ dinv,
                                              u32* __restrict__ ec) {
    __shared__ u32 rbuf[CAP];
    __shared__ u32 obuf[CAP];
    __shared__ int bc[256];
    __shared__ int ncnt[256];
    __shared__ int a[256];
    __shared__ int ncur[256];
    int tid = threadIdx.x, b = blockIdx.x;

    // bucket-count scan (every block computes the same 196-prefix)
    int c = 0;
    if (tid < NB) { c = gcursor[tid]; if (c > CAP) c = CAP; }
    bc[tid] = c;
    __syncthreads();
    for (int off = 1; off < 256; off <<= 1) {
        int add = (tid >= off) ? bc[tid - off] : 0;
        __syncthreads();
        bc[tid] += add;
        __syncthreads();
    }
    if (b == 0 && tid == NB - 1) starts[NN] = bc[tid];
    int cb = gcursor[b]; if (cb > CAP) cb = CAP;
    int lo = bc[b] - cb;
    int cnt = cb;

    const u32* src = recs + (size_t)b * CAP;
    for (int i = tid; i < cnt; i += BT) rbuf[i] = src[i];
    ncnt[tid] = 0;
    __syncthreads();
    for (int i = tid; i < cnt; i += BT) atomicAdd(&ncnt[rbuf[i] >> 24], 1);
    __syncthreads();
    a[tid] = ncnt[tid];
    __syncthreads();
    for (int off = 1; off < 256; off <<= 1) {
        int add = (tid >= off) ? a[tid - off] : 0;
        __syncthreads();
        a[tid] += add;
        __syncthreads();
    }
    int excl = a[tid] - ncnt[tid];
    ncur[tid] = excl;
    {
        int node = (b << 8) + tid;
        if (node < NN) {
            starts[node] = lo + excl;
            float d = (float)ncnt[tid] + 1.0f;
            dinv[node] = rsqrtf(d);
        }
    }
    __syncthreads();
    for (int i = tid; i < cnt; i += BT) {
        u32 rec = rbuf[i];
        int pos = atomicAdd(&ncur[rec >> 24], 1);
        if (pos >= 0 && pos < CAP) obuf[pos] = rec & 0xFFFFFFu;
    }
    __syncthreads();
    for (int i = tid; i < cnt; i += BT) ec[lo + i] = obuf[i];
}

// ---------------- MFMA GEMM, fused dinv row-scaling; pad rows scale=0 -> zeros ----------------
template<int K, bool CONVF32, bool SCALE_EXT>
__global__ __launch_bounds__(256) void k_gemm_mfma(const void* __restrict__ Ain,
                                                   const u16* __restrict__ Bt,
                                                   const float* __restrict__ rs,
                                                   u16* __restrict__ Cmain,
                                                   u16* __restrict__ Cext) {
    int lane = threadIdx.x & 63;
    int wv = threadIdx.x >> 6;
    int rbase = blockIdx.x * 64 + wv * 16;
    int lr = lane & 15;
    int kk = (lane >> 4) * 8;
    int arow = rbase + lr;
    if (CONVF32 && arow >= NN) arow = NN - 1;

    const u16* bp = Bt + (size_t)lr * K + kk;

    f32x4 acc[9] = {};
#pragma unroll
    for (int ks = 0; ks < K / 32; ++ks) {
        bf16x8 af;
        if (CONVF32) {
            const float* ap = (const float*)Ain + (size_t)arow * K + kk + ks * 32;
            float4 f0 = *(const float4*)ap;
            float4 f1 = *(const float4*)(ap + 4);
            union { uint4 u; bf16x8 v; } cv;
            cv.u.x = pack2(f0.x, f0.y); cv.u.y = pack2(f0.z, f0.w);
            cv.u.z = pack2(f1.x, f1.y); cv.u.w = pack2(f1.z, f1.w);
            af = cv.v;
        } else {
            af = *(const bf16x8*)((const u16*)Ain + (size_t)arow * K + kk + ks * 32);
        }
#pragma unroll
        for (int t = 0; t < 9; ++t) {
            bf16x8 bf = *(const bf16x8*)(bp + (size_t)(t * 16) * K + ks * 32);
            acc[t] = __builtin_amdgcn_mfma_f32_16x16x32_bf16(bf, af, acc[t], 0, 0, 0);
        }
    }

    int n0 = (lane >> 4) * 4;
    int crow = rbase + lr;
    float s = (crow < NN) ? rs[crow] : 0.0f;   // pad rows -> exact zeros
    u16* cm = Cmain + (size_t)crow * 128;
#pragma unroll
    for (int t = 0; t < 8; ++t) {
        ushort4 w;
        w.x = f2bf(acc[t][0] * s); w.y = f2bf(acc[t][1] * s);
        w.z = f2bf(acc[t][2] * s); w.w = f2bf(acc[t][3] * s);
        *(ushort4*)(cm + 16 * t + n0) = w;
    }
    if (n0 == 0) {
        float se = SCALE_EXT ? s : ((crow < NN) ? 1.0f : 0.0f);
        ushort4 w;
        w.x = f2bf(acc[8][0] * se); w.y = f2bf(acc[8][1] * se);
        w.z = f2bf(acc[8][2] * se); w.w = f2bf(acc[8][3] * se);
        *(ushort4*)(Cext + (size_t)crow * 4) = w;
    }
}

// ---------------- aggregates: quarter-wave row gathers, 16 rows in flight ----------------
// 2-wave blocks (AT=128): E[max-of-2] tail < E[max-of-4], body/VGPR unchanged.

__global__ __launch_bounds__(AT) void k_agg1(const u16* __restrict__ Hm,
                       const u16* __restrict__ Xp,
                       const int* __restrict__ starts, const u32* __restrict__ ec,
                       const float* __restrict__ dinv,
                       const float* __restrict__ b1, u16* __restrict__ outp) {
    int node = blockIdx.x * (blockDim.x >> 6) + (threadIdx.x >> 6);
    int lane = threadIdx.x & 63;
    if (node >= MPAD) return;
    int c16 = lane & 15;
    u32* orow = (u32*)(outp + (size_t)node * 160);
    if (node >= NN) {              // zero Hcat pad row
        if (lane < 16) {
            *(uint4*)(orow + c16 * 4) = make_uint4(0, 0, 0, 0);
            orow[64 + lane] = 0;
        }
        return;
    }
    int q = lane >> 4;
    int s = starts[node], e = starts[node + 1];

    float a0=0,a1=0,a2=0,a3=0,a4=0,a5=0,a6=0,a7=0;
    if (lane < 16) {
        uint4 v = *(const uint4*)(Hm + ((size_t)node << 7) + c16 * 8);
        a0 = bflo(v.x); a1 = bfhi(v.x); a2 = bflo(v.y); a3 = bfhi(v.y);
        a4 = bflo(v.z); a5 = bfhi(v.z); a6 = bflo(v.w); a7 = bfhi(v.w);
    }

    for (int g0 = s; g0 < e; g0 += 16) {
        u32 row[4];
#pragma unroll
        for (int grp = 0; grp < 4; ++grp) {
            int idx = g0 + grp * 4 + q;
            int ii = idx < e ? idx : e - 1;
            u32 r = ec[ii];
            row[grp] = (idx < e) ? r : (u32)ZR;
        }
        uint4 v[4];
#pragma unroll
        for (int grp = 0; grp < 4; ++grp)
            v[grp] = *(const uint4*)(Hm + ((size_t)row[grp] << 7) + c16 * 8);
#pragma unroll
        for (int grp = 0; grp < 4; ++grp) {
            a0 += bflo(v[grp].x); a1 += bfhi(v[grp].x);
            a2 += bflo(v[grp].y); a3 += bfhi(v[grp].y);
            a4 += bflo(v[grp].z); a5 += bfhi(v[grp].z);
            a6 += bflo(v[grp].w); a7 += bfhi(v[grp].w);
        }
    }

    a0 += __shfl_xor(a0, 16); a1 += __shfl_xor(a1, 16);
    a2 += __shfl_xor(a2, 16); a3 += __shfl_xor(a3, 16);
    a4 += __shfl_xor(a4, 16); a5 += __shfl_xor(a5, 16);
    a6 += __shfl_xor(a6, 16); a7 += __shfl_xor(a7, 16);
    a0 += __shfl_xor(a0, 32); a1 += __shfl_xor(a1, 32);
    a2 += __shfl_xor(a2, 32); a3 += __shfl_xor(a3, 32);
    a4 += __shfl_xor(a4, 32); a5 += __shfl_xor(a5, 32);
    a6 += __shfl_xor(a6, 32); a7 += __shfl_xor(a7, 32);

    float dc = dinv[node];
    float4 bA = *(const float4*)(b1 + c16 * 8);
    float4 bB = *(const float4*)(b1 + c16 * 8 + 4);
    float v0 = fmaxf(fmaf(dc, a0, bA.x), 0.f);
    float v1 = fmaxf(fmaf(dc, a1, bA.y), 0.f);
    float v2 = fmaxf(fmaf(dc, a2, bA.z), 0.f);
    float v3 = fmaxf(fmaf(dc, a3, bA.w), 0.f);
    float v4 = fmaxf(fmaf(dc, a4, bB.x), 0.f);
    float v5 = fmaxf(fmaf(dc, a5, bB.y), 0.f);
    float v6 = fmaxf(fmaf(dc, a6, bB.z), 0.f);
    float v7 = fmaxf(fmaf(dc, a7, bB.w), 0.f);

    if (lane < 16) {
        uint4 w = make_uint4(pack2(v0, v1), pack2(v2, v3), pack2(v4, v5), pack2(v6, v7));
        *(uint4*)(orow + c16 * 4) = w;
        orow[64 + lane] = (lane < 2) ? *(const u32*)(Xp + ((size_t)node << 2) + 2 * lane) : 0u;
    }
}

__global__ __launch_bounds__(AT) void k_agg2(const u16* __restrict__ Hm,
                       const u16* __restrict__ He,
                       const u16* __restrict__ Xp1,
                       const int* __restrict__ starts, const u32* __restrict__ ec,
                       const float* __restrict__ dinv,
                       const float* __restrict__ b2, float* __restrict__ outp) {
    int node = blockIdx.x * (blockDim.x >> 6) + (threadIdx.x >> 6);
    int lane = threadIdx.x & 63;
    if (node >= NN) return;
    int c16 = lane & 15;
    int q = lane >> 4;
    int s = starts[node], e = starts[node + 1];

    float a0=0,a1=0,a2=0,a3=0,a4=0,a5=0,a6=0,a7=0;
    float cx = 0.f, cy = 0.f;
    if (lane < 16) {
        uint4 v = *(const uint4*)(Hm + ((size_t)node << 7) + c16 * 8);
        a0 = bflo(v.x); a1 = bfhi(v.x); a2 = bflo(v.y); a3 = bfhi(v.y);
        a4 = bflo(v.z); a5 = bfhi(v.z); a6 = bflo(v.w); a7 = bfhi(v.w);
    }
    if (lane < 2) {
        u32 w = *(const u32*)(He + ((size_t)node << 2) + 2 * lane);
        cx = bflo(w); cy = bfhi(w);
    }

    for (int g0 = s; g0 < e; g0 += 16) {
        u32 row[4];
#pragma unroll
        for (int grp = 0; grp < 4; ++grp) {
            int idx = g0 + grp * 4 + q;
            int ii = idx < e ? idx : e - 1;
            u32 r = ec[ii];
            row[grp] = (idx < e) ? r : (u32)ZR;
        }
        uint4 v[4];
#pragma unroll
        for (int grp = 0; grp < 4; ++grp)
            v[grp] = *(const uint4*)(Hm + ((size_t)row[grp] << 7) + c16 * 8);
        if (c16 < 2) {
#pragma unroll
            for (int grp = 0; grp < 4; ++grp) {
                u32 w = *(const u32*)(He + ((size_t)row[grp] << 2) + 2 * (lane & 1));
                cx += bflo(w); cy += bfhi(w);
            }
        }
#pragma unroll
        for (int grp = 0; grp < 4; ++grp) {
            a0 += bflo(v[grp].x); a1 += bfhi(v[grp].x);
            a2 += bflo(v[grp].y); a3 += bfhi(v[grp].y);
            a4 += bflo(v[grp].z); a5 += bfhi(v[grp].z);
            a6 += bflo(v[grp].w); a7 += bfhi(v[grp].w);
        }
    }

    a0 += __shfl_xor(a0, 16); a1 += __shfl_xor(a1, 16);
    a2 += __shfl_xor(a2, 16); a3 += __shfl_xor(a3, 16);
    a4 += __shfl_xor(a4, 16); a5 += __shfl_xor(a5, 16);
    a6 += __shfl_xor(a6, 16); a7 += __shfl_xor(a7, 16);
    cx += __shfl_xor(cx, 16); cy += __shfl_xor(cy, 16);
    a0 += __shfl_xor(a0, 32); a1 += __shfl_xor(a1, 32);
    a2 += __shfl_xor(a2, 32); a3 += __shfl_xor(a3, 32);
    a4 += __shfl_xor(a4, 32); a5 += __shfl_xor(a5, 32);
    a6 += __shfl_xor(a6, 32); a7 += __shfl_xor(a7, 32);
    cx += __shfl_xor(cx, 32); cy += __shfl_xor(cy, 32);

    float dc = dinv[node];
    float* orow = outp + (size_t)node * 136;
    if (lane < 16) {
        float4 bA = *(const float4*)(b2 + c16 * 8);
        float4 bB = *(const float4*)(b2 + c16 * 8 + 4);
        float4 wA, wB;
        wA.x = fmaf(dc, a0, bA.x); wA.y = fmaf(dc, a1, bA.y);
        wA.z = fmaf(dc, a2, bA.z); wA.w = fmaf(dc, a3, bA.w);
        wB.x = fmaf(dc, a4, bB.x); wB.y = fmaf(dc, a5, bB.y);
        wB.z = fmaf(dc, a6, bB.z); wB.w = fmaf(dc, a7, bB.w);
        *(float4*)(orow + c16 * 8) = wA;
        *(float4*)(orow + c16 * 8 + 4) = wB;
    }
    if (lane < 2) {
        float2 bb = *(const float2*)(b2 + 128 + 2 * lane);
        *(float2*)(orow + 128 + 2 * lane) = make_float2(fmaf(dc, cx, bb.x), fmaf(dc, cy, bb.y));
        u32 up = *(const u32*)(Xp1 + ((size_t)node << 2) + 2 * lane);
        *(float2*)(orow + 132 + 2 * lane) = make_float2(bflo(up), bfhi(up));
    }
}

extern "C" void kernel_launch(void* const* d_in, const int* in_sizes, int n_in,
                              void* d_out, int out_size, void* d_ws, size_t ws_size,
                              hipStream_t stream) {
    const int*   ei = (const int*)d_in[0];
    const float* x  = (const float*)d_in[1];
    const float* Wp = (const float*)d_in[2];
    const float* W1 = (const float*)d_in[3];
    const float* b1 = (const float*)d_in[4];
    const float* W2 = (const float*)d_in[5];
    const float* b2 = (const float*)d_in[6];
    float* out = (float*)d_out;

    const int E = in_sizes[0] / 2;
    const int* erow = ei;
    const int* ecol = ei + E;

    // workspace layout
    char* p = (char*)d_ws;
    u16* H1main = (u16*)p; p += (size_t)MPAD * 128 * 2;  // conv1 h' (scaled); reused as H2main
    u16* Hcat   = (u16*)p; p += (size_t)MPAD * 160 * 2;  // h1cat bf16
    u16* Xp1    = (u16*)p; p += (size_t)MPAD * 4 * 2;    // xproj bf16
    u16* H2ext  = (u16*)p; p += (size_t)MPAD * 4 * 2;    // h2' cols 128-131 (scaled)
    u16* W1t    = (u16*)p; p += 144 * 128 * 2;
    u16* W2t    = (u16*)p; p += 144 * 160 * 2;
    u32* recs   = (u32*)p; p += (size_t)NB * CAP * 4;    // fixed-capacity bucket regions
    u32* ec     = (u32*)p; p += (size_t)E * 4;           // compacted row-only records
    float* dinv = (float*)p; p += NN * 4;
    int* starts = (int*)p; p += (size_t)(NN + 1) * 4;
    int* gcursor= (int*)p; p += NB * 4;

    u16* H2main = H1main;

    const int T = 256;
    const int pblocks = (E + PT_TILE - 1) / PT_TILE;

    // fused prep (weights + cursor zero)
    const int prep_total = PREP_W1 + PREP_W2 + NB;
    k_prep<<<(prep_total + T - 1) / T, T, 0, stream>>>(W1, Wp, W2, W1t, W2t, gcursor);

    // CSR build: partition -> build (bscan folded into build)
    k_part<<<pblocks, PT_T, 0, stream>>>(erow, ecol, E, gcursor, recs);
    k_build<<<NB, BT, 0, stream>>>(recs, gcursor, starts, dinv, ec);

    const int gblocks = MPAD / 64;
    const int a1blocks = (MPAD + 1) / 2;   // 2 waves/block
    const int a2blocks = (NN + 1) / 2;

    // conv1: h' = dinv .* (x @ [W1|Wp]); pad rows = 0
    k_gemm_mfma<128, true, false><<<gblocks, T, 0, stream>>>(x, W1t, dinv, H1main, Xp1);
    k_agg1<<<a1blocks, AT, 0, stream>>>(H1main, Xp1, starts, ec, dinv, b1, Hcat);

    // conv2: h2' = dinv .* (h1cat @ W2); pad rows = 0 (incl. ext)
    k_gemm_mfma<160, false, true><<<gblocks, T, 0, stream>>>(Hcat, W2t, dinv, H2main, H2ext);
    k_agg2<<<a2blocks, AT, 0, stream>>>(H2main, H2ext, Xp1, starts, ec, dinv, b2, out);
}